// Round 4
// baseline (202.439 us; speedup 1.0000x reference)
//
#include <hip/hip_runtime.h>
#include <math.h>

// Hausdorff distance, B=16, N=4096, D=3, fp32.
// out[b] = 0.5*(max_gt min_pred d + max_pred min_gt d), d = ||p-q||^2
//
// R4:
//  - M=4 home pts/thread (16 live accum VGPRs): low enough register
//    pressure that the compiler keeps the natural j-outer loop (R2's
//    M=8 provoked loop interchange -> 8x LDS re-reads; R3's asm pin
//    serialized the scheduler -> latency-bound). No asm hacks.
//  - SPLIT=16 -> 2048 blocks -> 32 waves/CU (max occupancy) to hide
//    LDS broadcast latency between unrolled j-groups.
//  - ONE memset node + ONE kernel. hipMemsetAsync(ws, 0xFF) makes wsmin
//    slots 0xFFFFFFFF (acts as +inf for uint atomicMin since all d-bits
//    <= 0x7F800000) and gives counters a known base: atomicAdd wraps,
//    64th arrival observes old == 62 (BLOCKS_PER_DB-2), 32nd finisher
//    observes old == 30 (2*NB-2).
//  - half-distance dot form: acc = hq - p.q via 3 FMA (free neg mods)
//    + 1 min = 4 VALU/pair; hp folded in after the loop; clamp >= 0
//    keeps uint-bit atomicMin ordering exact.

#define NPTS 4096
#define NB 16
#define TPB 256
#define M 4                    // home points per thread
#define SPLIT 16               // opponent chunks
#define HT (TPB * M)           // 1024 home points per block
#define OC (NPTS / SPLIT)      // 256 opponent points per chunk
#define NHT (NPTS / HT)        // 4 home tiles
#define BLOCKS_PER_DB (NHT * SPLIT)   // 64 blocks per (dir, b)

// ws layout (uints): wsmin[2][NB][NPTS], ctr1[32], ctr2, partial[32]
#define WSMIN_N (2 * NB * NPTS)
#define CTR1_OFF WSMIN_N
#define CTR2_OFF (WSMIN_N + 32)
#define PART_OFF (WSMIN_N + 33)
#define WS_TOTAL (WSMIN_N + 65)

__global__ __launch_bounds__(TPB) void haus_scan_kernel(
        const float* __restrict__ preds, const float* __restrict__ gts,
        unsigned int* __restrict__ ws, float* __restrict__ out) {
    const int ht  = blockIdx.x & (NHT - 1);    // home tile index
    const int oc  = blockIdx.x >> 2;           // opponent chunk index (NHT==4)
    const int b   = blockIdx.y;
    const int dir = blockIdx.z;                // 0: home=gts scan preds; 1: home=preds scan gts
    const int t   = threadIdx.x;

    const float* home = (dir == 0) ? gts : preds;
    const float* opp  = (dir == 0) ? preds : gts;
    const float* hb = home + (size_t)b * NPTS * 3;
    const float* ob = opp  + (size_t)b * NPTS * 3;

    // stage opponent chunk: (qx,qy,qz, hq=|q|^2/2), one point per thread
    __shared__ float4 q[OC];
    {
        const float* src = ob + (size_t)(oc * OC + t) * 3;
        float qx = src[0], qy = src[1], qz = src[2];
        float hq = 0.5f * fmaf(qx, qx, fmaf(qy, qy, qz * qz));
        q[t] = make_float4(qx, qy, qz, hq);
    }

    float px[M], py[M], pz[M], best[M];
#pragma unroll
    for (int k = 0; k < M; ++k) {
        int hi = ht * HT + k * TPB + t;
        px[k] = hb[hi * 3 + 0];
        py[k] = hb[hi * 3 + 1];
        pz[k] = hb[hi * 3 + 2];
        best[k] = INFINITY;
    }

    __syncthreads();

#pragma unroll 4
    for (int j = 0; j < OC; ++j) {
        float4 qq = q[j];                      // wave-uniform -> LDS broadcast
#pragma unroll
        for (int k = 0; k < M; ++k) {
            float acc = fmaf(-px[k], qq.x, qq.w);  // hq - p.q
            acc = fmaf(-py[k], qq.y, acc);
            acc = fmaf(-pz[k], qq.z, acc);
            best[k] = fminf(best[k], acc);
        }
    }

    unsigned int* slot = ws + ((size_t)dir * NB + b) * NPTS;
#pragma unroll
    for (int k = 0; k < M; ++k) {
        int hi = ht * HT + k * TPB + t;
        float hp = 0.5f * fmaf(px[k], px[k], fmaf(py[k], py[k], pz[k] * pz[k]));
        float d2 = fmaxf(best[k] + hp, 0.0f);  // >=0 so uint order == float order
        atomicMin(slot + hi, __float_as_uint(d2));
    }

    // ---- fused reduction: last block per (dir,b), then global last ----
    __threadfence();                            // release this block's atomics
    __shared__ bool s_last;
    __syncthreads();
    if (t == 0) {
        unsigned old = atomicAdd(&ws[CTR1_OFF + dir * NB + b], 1u);
        // counters start at 0xFFFFFFFF (memset 0xFF): 64th arrival sees 62
        s_last = (old == BLOCKS_PER_DB - 2u);
    }
    __syncthreads();
    if (!s_last) return;

    __threadfence();                            // acquire all blocks' mins
    const unsigned int* basep = ws + ((size_t)dir * NB + b) * NPTS;
    unsigned mx = 0u;
#pragma unroll
    for (int r = 0; r < NPTS / TPB; ++r) {      // 16 per thread
        unsigned v = __hip_atomic_load(&basep[r * TPB + t], __ATOMIC_RELAXED,
                                       __HIP_MEMORY_SCOPE_AGENT);
        mx = mx > v ? mx : v;                   // uint max == float max (vals >= 0)
    }
#pragma unroll
    for (int off = 32; off > 0; off >>= 1) {
        unsigned o = (unsigned)__shfl_down((int)mx, off, 64);
        mx = mx > o ? mx : o;
    }
    __shared__ unsigned sred[4];
    if ((t & 63) == 0) sred[t >> 6] = mx;
    __syncthreads();
    if (t == 0) {
        unsigned m01 = sred[0] > sred[1] ? sred[0] : sred[1];
        unsigned m23 = sred[2] > sred[3] ? sred[2] : sred[3];
        unsigned m = m01 > m23 ? m01 : m23;
        __hip_atomic_store(&ws[PART_OFF + dir * NB + b], m, __ATOMIC_RELAXED,
                           __HIP_MEMORY_SCOPE_AGENT);
        __threadfence();                        // release partial
        unsigned old2 = atomicAdd(&ws[CTR2_OFF], 1u);
        // ctr2 starts at 0xFFFFFFFF: 32nd arrival sees 30
        s_last = (old2 == 2u * NB - 2u);
    }
    __syncthreads();
    if (!s_last) return;

    __threadfence();                            // acquire partials
    if (t < NB) {
        unsigned u0 = __hip_atomic_load(&ws[PART_OFF + 0 * NB + t], __ATOMIC_RELAXED,
                                        __HIP_MEMORY_SCOPE_AGENT);
        unsigned u1 = __hip_atomic_load(&ws[PART_OFF + 1 * NB + t], __ATOMIC_RELAXED,
                                        __HIP_MEMORY_SCOPE_AGENT);
        // values are half squared distances: sum == 0.5*(loss1+loss2)
        out[t] = __uint_as_float(u0) + __uint_as_float(u1);
    }
}

extern "C" void kernel_launch(void* const* d_in, const int* in_sizes, int n_in,
                              void* d_out, int out_size, void* d_ws, size_t ws_size,
                              hipStream_t stream) {
    const float* preds = (const float*)d_in[0];
    const float* gts   = (const float*)d_in[1];
    float* out = (float*)d_out;
    unsigned int* ws = (unsigned int*)d_ws;     // 512 KB + 65 uints used

    // 0xFF fill: wsmin slots -> 0xFFFFFFFF (+inf for uint atomicMin),
    // counters -> known base for wrapping atomicAdd arrival detection.
    hipMemsetAsync(ws, 0xFF, (size_t)WS_TOTAL * sizeof(unsigned int), stream);

    haus_scan_kernel<<<dim3(NHT * SPLIT, NB, 2), dim3(TPB), 0, stream>>>(
        preds, gts, ws, out);
}

// Round 5
// 97.538 us; speedup vs baseline: 2.0755x; 2.0755x over previous
//
#include <hip/hip_runtime.h>
#include <math.h>

// Hausdorff distance, B=16, N=4096, D=3, fp32.
// out[b] = 0.5*(max_gt min_pred d + max_pred min_gt d), d = ||p-q||^2
//
// R5:
//  - REVERTED fused reduction tail (R3/R4 regression root cause: per-block
//    __threadfence() device-scope fences -> buffer_wbl2/buffer_inv L2
//    maintenance serialized the whole kernel; 2048 blocks x 2 fences).
//    Back to: memset node (ws init) + scan kernel + tiny final kernel.
//  - M=8 home pts/thread + NON-volatile empty asm pin on staged q:
//    R2 showed the compiler remats q[j] from LDS per home point
//    (VGPR=36 -> 1 ds_read per 4 VALU, co-saturation at 46 us).
//    Non-volatile asm is schedulable (R3's volatile pin serialized
//    the pipeline) but not rematerializable -> q stays in VGPRs,
//    1 ds_read_b128 per 32 VALU.
//  - half-distance dot form: acc = hq - p.q via 3 FMA (free neg mods)
//    + 1 min = 4 VALU/pair; hp folded in post-loop; clamp >= 0 keeps
//    uint-bit atomicMin ordering exact.
//  - memset 0xFF: wsmin slots = 0xFFFFFFFF > any finite d2 bits, so it
//    acts as +inf for uint atomicMin.

#define NPTS 4096
#define NB 16
#define TPB 256
#define M 8                    // home points per thread
#define SPLIT 16               // opponent chunks
#define HT (TPB * M)           // 2048 home points per block
#define OC (NPTS / SPLIT)      // 256 opponent points per chunk
#define NHT (NPTS / HT)        // 2 home tiles

#define WSMIN_N (2 * NB * NPTS)

__global__ __launch_bounds__(TPB) void haus_scan_kernel(
        const float* __restrict__ preds, const float* __restrict__ gts,
        unsigned int* __restrict__ wsmin) {
    const int ht  = blockIdx.x & (NHT - 1);    // home tile index
    const int oc  = blockIdx.x >> 1;           // opponent chunk index (NHT==2)
    const int b   = blockIdx.y;
    const int dir = blockIdx.z;                // 0: home=gts scan preds; 1: home=preds scan gts
    const int t   = threadIdx.x;

    const float* home = (dir == 0) ? gts : preds;
    const float* opp  = (dir == 0) ? preds : gts;
    const float* hb = home + (size_t)b * NPTS * 3;
    const float* ob = opp  + (size_t)b * NPTS * 3;

    // stage opponent chunk: (qx,qy,qz, hq=|q|^2/2), one point per thread
    __shared__ float4 q[OC];
    {
        const float* src = ob + (size_t)(oc * OC + t) * 3;
        float qx = src[0], qy = src[1], qz = src[2];
        float hq = 0.5f * fmaf(qx, qx, fmaf(qy, qy, qz * qz));
        q[t] = make_float4(qx, qy, qz, hq);
    }

    float px[M], py[M], pz[M], best[M];
#pragma unroll
    for (int k = 0; k < M; ++k) {
        int hi = ht * HT + k * TPB + t;
        px[k] = hb[hi * 3 + 0];
        py[k] = hb[hi * 3 + 1];
        pz[k] = hb[hi * 3 + 2];
        best[k] = INFINITY;
    }

    __syncthreads();

#pragma unroll 4
    for (int j = 0; j < OC; ++j) {
        float4 q4 = q[j];                      // wave-uniform -> ds_read_b128 broadcast
        float qx = q4.x, qy = q4.y, qz = q4.z, qw = q4.w;
        // NON-volatile opaque pin: keeps qx..qw live in VGPRs (cannot be
        // rematerialized from LDS per home point) while remaining freely
        // schedulable (R3's volatile version serialized the pipeline).
        asm("" : "+v"(qx), "+v"(qy), "+v"(qz), "+v"(qw));
#pragma unroll
        for (int k = 0; k < M; ++k) {
            float acc = fmaf(-px[k], qx, qw);  // hq - p.q
            acc = fmaf(-py[k], qy, acc);
            acc = fmaf(-pz[k], qz, acc);
            best[k] = fminf(best[k], acc);
        }
    }

    unsigned int* slot = wsmin + ((size_t)dir * NB + b) * NPTS;
#pragma unroll
    for (int k = 0; k < M; ++k) {
        int hi = ht * HT + k * TPB + t;
        float hp = 0.5f * fmaf(px[k], px[k], fmaf(py[k], py[k], pz[k] * pz[k]));
        float d2 = fmaxf(best[k] + hp, 0.0f);  // >=0 so uint order == float order
        atomicMin(slot + hi, __float_as_uint(d2));
    }
}

__global__ __launch_bounds__(TPB) void haus_final_kernel(
        const unsigned int* __restrict__ wsmin, float* __restrict__ out) {
    const int b = blockIdx.x;
    const int t = threadIdx.x;
    const float4* w0 = (const float4*)(wsmin + ((size_t)0 * NB + b) * NPTS);
    const float4* w1 = (const float4*)(wsmin + ((size_t)1 * NB + b) * NPTS);
    float m1 = -INFINITY, m2 = -INFINITY;
#pragma unroll
    for (int r = 0; r < NPTS / 4 / TPB; ++r) {   // 4 float4 per thread
        float4 a = w0[r * TPB + t];
        float4 c = w1[r * TPB + t];
        m1 = fmaxf(fmaxf(fmaxf(a.x, a.y), fmaxf(a.z, a.w)), m1);
        m2 = fmaxf(fmaxf(fmaxf(c.x, c.y), fmaxf(c.z, c.w)), m2);
    }
#pragma unroll
    for (int off = 32; off > 0; off >>= 1) {
        m1 = fmaxf(m1, __shfl_down(m1, off, 64));
        m2 = fmaxf(m2, __shfl_down(m2, off, 64));
    }
    __shared__ float s1[4], s2[4];
    if ((t & 63) == 0) { s1[t >> 6] = m1; s2[t >> 6] = m2; }
    __syncthreads();
    if (t == 0) {
        float a = fmaxf(fmaxf(s1[0], s1[1]), fmaxf(s1[2], s1[3]));
        float c = fmaxf(fmaxf(s2[0], s2[1]), fmaxf(s2[2], s2[3]));
        out[b] = a + c;   // values are d/2, so sum == 0.5*(loss1+loss2)
    }
}

extern "C" void kernel_launch(void* const* d_in, const int* in_sizes, int n_in,
                              void* d_out, int out_size, void* d_ws, size_t ws_size,
                              hipStream_t stream) {
    const float* preds = (const float*)d_in[0];
    const float* gts   = (const float*)d_in[1];
    float* out = (float*)d_out;
    unsigned int* wsmin = (unsigned int*)d_ws;   // 512 KB used

    // 0xFF fill = +inf sentinel for uint atomicMin (all finite d2 bits smaller)
    hipMemsetAsync(wsmin, 0xFF, (size_t)WSMIN_N * sizeof(unsigned int), stream);

    haus_scan_kernel<<<dim3(NHT * SPLIT, NB, 2), dim3(TPB), 0, stream>>>(
        preds, gts, wsmin);

    haus_final_kernel<<<dim3(NB), dim3(TPB), 0, stream>>>(wsmin, out);
}

// Round 6
// 96.472 us; speedup vs baseline: 2.0984x; 1.0110x over previous
//
#include <hip/hip_runtime.h>
#include <math.h>

// Hausdorff distance, B=16, N=4096, D=3, fp32.
// out[b] = 0.5*(max_gt min_pred d + max_pred min_gt d), d = ||p-q||^2
//
// R6: packed-FP32 inner loop. R1..R5 established the scan is VALU-issue
// bound at the measured scalar v_fma_f32 rate (m07: 103 TF, ~3cyc/wave64;
// every variant landed at op-count ratio: 7-op=84us, 4-op=46-49us).
// v_pk_fma_f32 (VOP3P packed fp32, CDNA2+) does 2 FMAs/instr:
//  - LDS opponent staging in SoA (qx[],qy[],qz[],qh[]) so TWO opponent
//    points load as one ds_read_b64 per coordinate (no repack movs).
//  - home coords pre-negated and broadcast into v2f pairs ONCE pre-loop,
//    pinned with non-volatile empty asm (R5-proven: schedulable, not
//    remat-able) so the 24 one-time movs can't be sunk into the loop.
//  - per (home k, opp pair jj): 3 v_pk_fma_f32 + 2 v_min_f32
//    = 2.5 VALU slots per pair (was 4).
// Scaffolding unchanged from R5 (memset 0xFF + scan + final); fixed
// ~45us replay overhead is node-count-invariant (R4 evidence).

#define NPTS 4096
#define NB 16
#define TPB 256
#define M 8                    // home points per thread
#define SPLIT 16               // opponent chunks
#define HT (TPB * M)           // 2048 home points per block
#define OC (NPTS / SPLIT)      // 256 opponent points per chunk
#define NHT (NPTS / HT)        // 2 home tiles

#define WSMIN_N (2 * NB * NPTS)

typedef float v2f __attribute__((ext_vector_type(2)));

__global__ __launch_bounds__(TPB) void haus_scan_kernel(
        const float* __restrict__ preds, const float* __restrict__ gts,
        unsigned int* __restrict__ wsmin) {
    const int ht  = blockIdx.x & (NHT - 1);    // home tile index
    const int oc  = blockIdx.x >> 1;           // opponent chunk index (NHT==2)
    const int b   = blockIdx.y;
    const int dir = blockIdx.z;                // 0: home=gts scan preds; 1: home=preds scan gts
    const int t   = threadIdx.x;

    const float* home = (dir == 0) ? gts : preds;
    const float* opp  = (dir == 0) ? preds : gts;
    const float* hb = home + (size_t)b * NPTS * 3;
    const float* ob = opp  + (size_t)b * NPTS * 3;

    // SoA staging: two consecutive opponent points per ds_read_b64
    __shared__ float sq[4][OC];                // [x|y|z|h][point]
    {
        const float* src = ob + (size_t)(oc * OC + t) * 3;
        float qx = src[0], qy = src[1], qz = src[2];
        sq[0][t] = qx; sq[1][t] = qy; sq[2][t] = qz;
        sq[3][t] = 0.5f * fmaf(qx, qx, fmaf(qy, qy, qz * qz));
    }

    // home points: pre-negated, broadcast into packed pairs (one-time)
    v2f pxn[M], pyn[M], pzn[M], best2[M];
#pragma unroll
    for (int k = 0; k < M; ++k) {
        int hi = ht * HT + k * TPB + t;
        float x = hb[hi * 3 + 0];
        float y = hb[hi * 3 + 1];
        float z = hb[hi * 3 + 2];
        pxn[k][0] = -x; pxn[k][1] = -x;
        pyn[k][0] = -y; pyn[k][1] = -y;
        pzn[k][0] = -z; pzn[k][1] = -z;
        // opaque (non-volatile) pin: the broadcast movs are one-time; this
        // stops the register allocator rematerializing them inside the loop.
        asm("" : "+v"(pxn[k]), "+v"(pyn[k]), "+v"(pzn[k]));
        best2[k][0] = INFINITY; best2[k][1] = INFINITY;
    }

    __syncthreads();

    const v2f* sqx = (const v2f*)sq[0];
    const v2f* sqy = (const v2f*)sq[1];
    const v2f* sqz = (const v2f*)sq[2];
    const v2f* sqh = (const v2f*)sq[3];

#pragma unroll 2
    for (int jj = 0; jj < OC / 2; ++jj) {      // two opponent points / iter
        v2f qx2 = sqx[jj];                     // wave-uniform ds_read_b64
        v2f qy2 = sqy[jj];
        v2f qz2 = sqz[jj];
        v2f qh2 = sqh[jj];
#pragma unroll
        for (int k = 0; k < M; ++k) {
            v2f acc;
            // acc = hq - p.q for two opponents at once
            asm("v_pk_fma_f32 %0, %1, %2, %3"
                : "=v"(acc) : "v"(pxn[k]), "v"(qx2), "v"(qh2));
            asm("v_pk_fma_f32 %0, %1, %2, %0"
                : "+v"(acc) : "v"(pyn[k]), "v"(qy2));
            asm("v_pk_fma_f32 %0, %1, %2, %0"
                : "+v"(acc) : "v"(pzn[k]), "v"(qz2));
            best2[k][0] = fminf(best2[k][0], acc[0]);
            best2[k][1] = fminf(best2[k][1], acc[1]);
        }
    }

    unsigned int* slot = wsmin + ((size_t)dir * NB + b) * NPTS;
#pragma unroll
    for (int k = 0; k < M; ++k) {
        int hi = ht * HT + k * TPB + t;
        float x = pxn[k][0], y = pyn[k][0], z = pzn[k][0];  // negated; squares fine
        float hp = 0.5f * fmaf(x, x, fmaf(y, y, z * z));
        float best = fminf(best2[k][0], best2[k][1]);
        float d2 = fmaxf(best + hp, 0.0f);     // >=0 so uint order == float order
        atomicMin(slot + hi, __float_as_uint(d2));
    }
}

__global__ __launch_bounds__(TPB) void haus_final_kernel(
        const unsigned int* __restrict__ wsmin, float* __restrict__ out) {
    const int b = blockIdx.x;
    const int t = threadIdx.x;
    const float4* w0 = (const float4*)(wsmin + ((size_t)0 * NB + b) * NPTS);
    const float4* w1 = (const float4*)(wsmin + ((size_t)1 * NB + b) * NPTS);
    float m1 = -INFINITY, m2 = -INFINITY;
#pragma unroll
    for (int r = 0; r < NPTS / 4 / TPB; ++r) {   // 4 float4 per thread
        float4 a = w0[r * TPB + t];
        float4 c = w1[r * TPB + t];
        m1 = fmaxf(fmaxf(fmaxf(a.x, a.y), fmaxf(a.z, a.w)), m1);
        m2 = fmaxf(fmaxf(fmaxf(c.x, c.y), fmaxf(c.z, c.w)), m2);
    }
#pragma unroll
    for (int off = 32; off > 0; off >>= 1) {
        m1 = fmaxf(m1, __shfl_down(m1, off, 64));
        m2 = fmaxf(m2, __shfl_down(m2, off, 64));
    }
    __shared__ float s1[4], s2[4];
    if ((t & 63) == 0) { s1[t >> 6] = m1; s2[t >> 6] = m2; }
    __syncthreads();
    if (t == 0) {
        float a = fmaxf(fmaxf(s1[0], s1[1]), fmaxf(s1[2], s1[3]));
        float c = fmaxf(fmaxf(s2[0], s2[1]), fmaxf(s2[2], s2[3]));
        out[b] = a + c;   // values are d/2, so sum == 0.5*(loss1+loss2)
    }
}

extern "C" void kernel_launch(void* const* d_in, const int* in_sizes, int n_in,
                              void* d_out, int out_size, void* d_ws, size_t ws_size,
                              hipStream_t stream) {
    const float* preds = (const float*)d_in[0];
    const float* gts   = (const float*)d_in[1];
    float* out = (float*)d_out;
    unsigned int* wsmin = (unsigned int*)d_ws;   // 512 KB used

    // 0xFF fill = +inf sentinel for uint atomicMin (all finite d2 bits smaller)
    hipMemsetAsync(wsmin, 0xFF, (size_t)WSMIN_N * sizeof(unsigned int), stream);

    haus_scan_kernel<<<dim3(NHT * SPLIT, NB, 2), dim3(TPB), 0, stream>>>(
        preds, gts, wsmin);

    haus_final_kernel<<<dim3(NB), dim3(TPB), 0, stream>>>(wsmin, out);
}

// Round 7
// 95.708 us; speedup vs baseline: 2.1152x; 1.0080x over previous
//
#include <hip/hip_runtime.h>
#include <math.h>

// Hausdorff distance, B=16, N=4096, D=3, fp32.
// out[b] = 0.5*(max_gt min_pred d + max_pred min_gt d), d = ||p-q||^2
//
// R7: LDS-traffic-bound fix. R6 post-mortem: total LDS-pipe cycles
// (waves x OC x 14cyc/pt / 256 CU) = 47.8us == measured duration; the
// scan has been ds_read-issue bound since R2. LDS cycles scale as
// #waves ~ 1/M, so:
//  - pack TWO DIFFERENT home points per v2f pair (R6 wastefully
//    duplicated one home into both halves) -> M=16 homes/thread at only
//    ~64 home VGPRs; #waves halves (8192 -> 4096).
//  - opponent point stays wave-uniform in LDS as (x,y),(z,h) v2f pairs:
//    VOP3P op_sel/op_sel_hi broadcasts one 32-bit half of a q pair into
//    both lanes of the packed op -> NO duplication movs, NO extra LDS.
//      fma1: acc = phx*(x,x) + (h,h)   op_sel:[0,0,1] op_sel_hi:[1,0,1]
//      fma2: acc = phy*(y,y) + acc     op_sel:[0,1,0] op_sel_hi:[1,1,1]
//      fma3: acc = phz*(z,z) + acc     op_sel:[0,0,0] op_sel_hi:[1,0,1]
//  - budget: LDS 4096x128x14/256 = 12us < VALU 17us -> VALU-bound.
//  - SPLIT=32 -> 1024 blocks -> 4 waves/SIMD.
// Scaffold: memset 0xFF (+inf sentinel) + scan + final (fences stay
// banned per R3/R4; node count is overhead-invariant per R4).

#define NPTS 4096
#define NB 16
#define TPB 256
#define M 16                   // home points per thread (8 packed pairs)
#define MP (M / 2)
#define SPLIT 32               // opponent chunks
#define OC (NPTS / SPLIT)      // 128 opponent points per chunk

#define WSMIN_N (2 * NB * NPTS)

typedef float v2f __attribute__((ext_vector_type(2)));

__global__ __launch_bounds__(TPB) void haus_scan_kernel(
        const float* __restrict__ preds, const float* __restrict__ gts,
        unsigned int* __restrict__ wsmin) {
    const int oc  = blockIdx.x;                // opponent chunk index
    const int b   = blockIdx.y;
    const int dir = blockIdx.z;                // 0: home=gts scan preds; 1: home=preds scan gts
    const int t   = threadIdx.x;

    const float* home = (dir == 0) ? gts : preds;
    const float* opp  = (dir == 0) ? preds : gts;
    const float* hb = home + (size_t)b * NPTS * 3;
    const float* ob = opp  + (size_t)b * NPTS * 3;

    // stage opponent chunk as (x,y) and (z,h) pairs, h = |q|^2/2
    __shared__ v2f sxy[OC], szh[OC];
    if (t < OC) {
        const float* src = ob + (size_t)(oc * OC + t) * 3;
        float qx = src[0], qy = src[1], qz = src[2];
        float hq = 0.5f * fmaf(qx, qx, fmaf(qy, qy, qz * qz));
        sxy[t] = (v2f){qx, qy};
        szh[t] = (v2f){qz, hq};
    }

    // home points: 2 per packed pair, pre-negated for the dot form
    v2f phx[MP], phy[MP], phz[MP], best2[MP];
#pragma unroll
    for (int kp = 0; kp < MP; ++kp) {
        int ha = (2 * kp) * TPB + t;           // covers all 4096 homes
        int hb_i = (2 * kp + 1) * TPB + t;
        phx[kp] = (v2f){-hb[ha * 3 + 0], -hb[hb_i * 3 + 0]};
        phy[kp] = (v2f){-hb[ha * 3 + 1], -hb[hb_i * 3 + 1]};
        phz[kp] = (v2f){-hb[ha * 3 + 2], -hb[hb_i * 3 + 2]};
        best2[kp] = (v2f){INFINITY, INFINITY};
    }

    __syncthreads();

#pragma unroll 2
    for (int j = 0; j < OC; ++j) {
        v2f qxy = sxy[j];                      // wave-uniform ds_read_b64
        v2f qzh = szh[j];
#pragma unroll
        for (int kp = 0; kp < MP; ++kp) {
            v2f acc;
            // acc = (h,h) - p.q for two home points at once
            asm("v_pk_fma_f32 %0, %1, %2, %3 op_sel:[0,0,1] op_sel_hi:[1,0,1]"
                : "=v"(acc) : "v"(phx[kp]), "v"(qxy), "v"(qzh));
            asm("v_pk_fma_f32 %0, %1, %2, %0 op_sel:[0,1,0] op_sel_hi:[1,1,1]"
                : "+v"(acc) : "v"(phy[kp]), "v"(qxy));
            asm("v_pk_fma_f32 %0, %1, %2, %0 op_sel:[0,0,0] op_sel_hi:[1,0,1]"
                : "+v"(acc) : "v"(phz[kp]), "v"(qzh));
            best2[kp][0] = fminf(best2[kp][0], acc[0]);
            best2[kp][1] = fminf(best2[kp][1], acc[1]);
        }
    }

    unsigned int* slot = wsmin + ((size_t)dir * NB + b) * NPTS;
#pragma unroll
    for (int kp = 0; kp < MP; ++kp) {
        int ha = (2 * kp) * TPB + t;
        int hb_i = (2 * kp + 1) * TPB + t;
        float xa = phx[kp][0], ya = phy[kp][0], za = phz[kp][0];  // negated; squares fine
        float xb = phx[kp][1], yb = phy[kp][1], zb = phz[kp][1];
        float hpa = 0.5f * fmaf(xa, xa, fmaf(ya, ya, za * za));
        float hpb = 0.5f * fmaf(xb, xb, fmaf(yb, yb, zb * zb));
        float da = fmaxf(best2[kp][0] + hpa, 0.0f);   // >=0: uint order == float order
        float db = fmaxf(best2[kp][1] + hpb, 0.0f);
        atomicMin(slot + ha, __float_as_uint(da));
        atomicMin(slot + hb_i, __float_as_uint(db));
    }
}

__global__ __launch_bounds__(TPB) void haus_final_kernel(
        const unsigned int* __restrict__ wsmin, float* __restrict__ out) {
    const int b = blockIdx.x;
    const int t = threadIdx.x;
    const float4* w0 = (const float4*)(wsmin + ((size_t)0 * NB + b) * NPTS);
    const float4* w1 = (const float4*)(wsmin + ((size_t)1 * NB + b) * NPTS);
    float m1 = -INFINITY, m2 = -INFINITY;
#pragma unroll
    for (int r = 0; r < NPTS / 4 / TPB; ++r) {   // 4 float4 per thread
        float4 a = w0[r * TPB + t];
        float4 c = w1[r * TPB + t];
        m1 = fmaxf(fmaxf(fmaxf(a.x, a.y), fmaxf(a.z, a.w)), m1);
        m2 = fmaxf(fmaxf(fmaxf(c.x, c.y), fmaxf(c.z, c.w)), m2);
    }
#pragma unroll
    for (int off = 32; off > 0; off >>= 1) {
        m1 = fmaxf(m1, __shfl_down(m1, off, 64));
        m2 = fmaxf(m2, __shfl_down(m2, off, 64));
    }
    __shared__ float s1[4], s2[4];
    if ((t & 63) == 0) { s1[t >> 6] = m1; s2[t >> 6] = m2; }
    __syncthreads();
    if (t == 0) {
        float a = fmaxf(fmaxf(s1[0], s1[1]), fmaxf(s1[2], s1[3]));
        float c = fmaxf(fmaxf(s2[0], s2[1]), fmaxf(s2[2], s2[3]));
        out[b] = a + c;   // values are d/2, so sum == 0.5*(loss1+loss2)
    }
}

extern "C" void kernel_launch(void* const* d_in, const int* in_sizes, int n_in,
                              void* d_out, int out_size, void* d_ws, size_t ws_size,
                              hipStream_t stream) {
    const float* preds = (const float*)d_in[0];
    const float* gts   = (const float*)d_in[1];
    float* out = (float*)d_out;
    unsigned int* wsmin = (unsigned int*)d_ws;   // 512 KB used

    // 0xFF fill = +inf sentinel for uint atomicMin (all finite d2 bits smaller)
    hipMemsetAsync(wsmin, 0xFF, (size_t)WSMIN_N * sizeof(unsigned int), stream);

    haus_scan_kernel<<<dim3(SPLIT, NB, 2), dim3(TPB), 0, stream>>>(
        preds, gts, wsmin);

    haus_final_kernel<<<dim3(NB), dim3(TPB), 0, stream>>>(wsmin, out);
}

// Round 9
// 93.299 us; speedup vs baseline: 2.1698x; 1.0258x over previous
//
#include <hip/hip_runtime.h>
#include <math.h>

// Hausdorff distance, B=16, N=4096, D=3, fp32.
// out[b] = 0.5*(max_gt min_pred d + max_pred min_gt d), d = ||p-q||^2
//
// R9 = R8 with the factor-of-2 bug fixed (R8 stored HALF norms with a
// FULL -2 dot -> v = d/2 - g.p, negative min for every home point ->
// clamp -> out==0, the exact observed absmax=3.92 signature).
// Now: B-side carries FULL hp=|p|^2 (split hi/lo in k9/k10), hg=|g|^2
// added in fp32 at the end -> wsmin holds true d; final kernel's 0.5
// produces the reference value.
//
// MFMA formulation (v_mfma_f32_32x32x16_f16, one 32x32 pair tile per
// instruction): d(m,n) = hg[m] + (hp[n] - 2 g_m . p_n); hi/lo f16 split
//   k0..2: (-2g_hi)*(p_hi)   k3..5: (-2g_hi)*(p_lo)
//   k6..8: (-2g_lo)*(p_hi)   k9,k10: 1 * hp_{hi,lo}
// (g_lo*p_lo ~1e-5 dropped) => fp32-level accuracy.
// A layout: A[m=lane&31][k=8*(lane>>5)+j]; B: same with n=lane&31.
// C/D (HW-verified m74/m101): col=lane&31, row=(reg&3)+8*(reg>>2)+4*(lane>>5).
// Min over opponents = min over cols: per-lane v_min on 16 accs, then
// butterfly within each 32-lane half (rows fixed per lane-half).
//
// SPLIT=4 -> OPP=1024 staged opponents, LDS ~33KB -> 4 blocks/CU.
// Pipe budget: LDS 10.2us (critical), VALU 6.8us, MFMA 1.7us.

#define NPTS 4096
#define NB 16
#define TPB 256
#define WAVES 4
#define HPW 32                    // homes per wave (MFMA M)
#define HPB (WAVES * HPW)         // 128 homes per block
#define NHB (NPTS / HPB)          // 32 home blocks
#define SPLIT 4
#define OPP (NPTS / SPLIT)        // 1024 opponents staged per block
#define TILES (OPP / 32)          // 32 MFMA tiles per wave

#define WSMIN_N (2 * NB * NPTS)

typedef _Float16 h8 __attribute__((ext_vector_type(8)));
typedef float f16v __attribute__((ext_vector_type(16)));

__global__ __launch_bounds__(TPB) void haus_scan_kernel(
        const float* __restrict__ preds, const float* __restrict__ gts,
        unsigned int* __restrict__ wsmin) {
    const int hb  = blockIdx.x & (NHB - 1);
    const int sp  = blockIdx.x >> 5;          // NHB == 32
    const int b   = blockIdx.y;
    const int dir = blockIdx.z;               // 0: home=gts vs preds; 1: home=preds vs gts
    const int t   = threadIdx.x;
    const int lane = t & 63, w = t >> 6;
    const int l31 = lane & 31, half = lane >> 5;

    const float* home = (dir == 0) ? gts : preds;
    const float* opp  = (dir == 0) ? preds : gts;
    const float* hbp = home + (size_t)b * NPTS * 3;
    const float* obp = opp  + (size_t)b * NPTS * 3;

    __shared__ h8 srec[2 * OPP];              // [khalf][point] B-form records
    __shared__ float shg[WAVES][HPW];

    // ---- stage opponents: B-form hi/lo records (FULL |p|^2) ----
    for (int i = 0; i < OPP / TPB; ++i) {
        int p = i * TPB + t;
        const float* s = obp + (size_t)(sp * OPP + p) * 3;
        float x = s[0], y = s[1], z = s[2];
        float hp = fmaf(x, x, fmaf(y, y, z * z));       // FULL norm (R8 fix)
        _Float16 xh = (_Float16)x, yh = (_Float16)y, zh = (_Float16)z;
        _Float16 xl = (_Float16)(x - (float)xh);
        _Float16 yl = (_Float16)(y - (float)yh);
        _Float16 zl = (_Float16)(z - (float)zh);
        _Float16 hph = (_Float16)hp, hpl = (_Float16)(hp - (float)hph);
        h8 lo, hi;
        lo[0] = xh; lo[1] = yh; lo[2] = zh;       // k0..2: p_hi
        lo[3] = xl; lo[4] = yl; lo[5] = zl;       // k3..5: p_lo
        lo[6] = xh; lo[7] = yh;                   // k6..7: p_hi (x,y) again
        hi[0] = zh;                               // k8: p_hi z
        hi[1] = hph; hi[2] = hpl;                 // k9..10: hp split
        hi[3] = (_Float16)0; hi[4] = (_Float16)0;
        hi[5] = (_Float16)0; hi[6] = (_Float16)0; hi[7] = (_Float16)0;
        srec[p] = lo;
        srec[OPP + p] = hi;
    }

    // ---- A-frag: 32 homes per wave, -2 * hi/lo split ----
    int m = hb * HPB + w * HPW + l31;
    float gx = hbp[m * 3 + 0], gy = hbp[m * 3 + 1], gz = hbp[m * 3 + 2];
    float hg = fmaf(gx, gx, fmaf(gy, gy, gz * gz));     // FULL norm (R8 fix)
    shg[w][l31] = hg;                         // lanes m and m+32 write same value
    _Float16 gxh = (_Float16)gx, gyh = (_Float16)gy, gzh = (_Float16)gz;
    _Float16 gxl = (_Float16)(gx - (float)gxh);
    _Float16 gyl = (_Float16)(gy - (float)gyh);
    _Float16 gzl = (_Float16)(gz - (float)gzh);
    const _Float16 n2 = (_Float16)(-2.0f);
    h8 afrag;
    if (half == 0) {                          // k0..7
        afrag[0] = n2 * gxh; afrag[1] = n2 * gyh; afrag[2] = n2 * gzh;
        afrag[3] = n2 * gxh; afrag[4] = n2 * gyh; afrag[5] = n2 * gzh;
        afrag[6] = n2 * gxl; afrag[7] = n2 * gyl;
    } else {                                  // k8..15
        afrag[0] = n2 * gzl;
        afrag[1] = (_Float16)1; afrag[2] = (_Float16)1;
        afrag[3] = (_Float16)0; afrag[4] = (_Float16)0;
        afrag[5] = (_Float16)0; afrag[6] = (_Float16)0; afrag[7] = (_Float16)0;
    }

    f16v zc = {};                             // zero C
    float best[16];
#pragma unroll
    for (int r = 0; r < 16; ++r) best[r] = INFINITY;

    __syncthreads();

    const int base = half * OPP + l31;        // srec index for this lane
#pragma unroll 2
    for (int tt = 0; tt < TILES; ++tt) {
        h8 bfrag = srec[base + tt * 32];      // one ds_read_b128, conflict-free
        f16v D = __builtin_amdgcn_mfma_f32_32x32x16_f16(afrag, bfrag, zc, 0, 0, 0);
#pragma unroll
        for (int r = 0; r < 16; ++r) best[r] = fminf(best[r], D[r]);
    }

    // ---- min over 32 cols: butterfly within each 32-lane half ----
#pragma unroll
    for (int off = 16; off >= 1; off >>= 1) {
#pragma unroll
        for (int r = 0; r < 16; ++r)
            best[r] = fminf(best[r], __shfl_xor(best[r], off, 64));
    }

    unsigned int* slot = wsmin + ((size_t)dir * NB + b) * NPTS + hb * HPB + w * HPW;
    if (l31 == 0) {                           // lanes 0 and 32: disjoint row sets
#pragma unroll
        for (int r = 0; r < 16; ++r) {
            int row = (r & 3) + 8 * (r >> 2) + 4 * half;
            float d = best[r] + shg[w][row];  // + |g|^2 in fp32 -> full d
            d = fmaxf(d, 0.0f);               // >=0: uint order == float order
            atomicMin(slot + row, __float_as_uint(d));
        }
    }
}

__global__ __launch_bounds__(TPB) void haus_final_kernel(
        const unsigned int* __restrict__ wsmin, float* __restrict__ out) {
    const int b = blockIdx.x;
    const int t = threadIdx.x;
    const float4* w0 = (const float4*)(wsmin + ((size_t)0 * NB + b) * NPTS);
    const float4* w1 = (const float4*)(wsmin + ((size_t)1 * NB + b) * NPTS);
    float m1 = -INFINITY, m2 = -INFINITY;
#pragma unroll
    for (int r = 0; r < NPTS / 4 / TPB; ++r) {   // 4 float4 per thread
        float4 a = w0[r * TPB + t];
        float4 c = w1[r * TPB + t];
        m1 = fmaxf(fmaxf(fmaxf(a.x, a.y), fmaxf(a.z, a.w)), m1);
        m2 = fmaxf(fmaxf(fmaxf(c.x, c.y), fmaxf(c.z, c.w)), m2);
    }
#pragma unroll
    for (int off = 32; off > 0; off >>= 1) {
        m1 = fmaxf(m1, __shfl_down(m1, off, 64));
        m2 = fmaxf(m2, __shfl_down(m2, off, 64));
    }
    __shared__ float s1[4], s2[4];
    if ((t & 63) == 0) { s1[t >> 6] = m1; s2[t >> 6] = m2; }
    __syncthreads();
    if (t == 0) {
        float a = fmaxf(fmaxf(s1[0], s1[1]), fmaxf(s1[2], s1[3]));
        float c = fmaxf(fmaxf(s2[0], s2[1]), fmaxf(s2[2], s2[3]));
        out[b] = 0.5f * (a + c);              // wsmin holds full d
    }
}

extern "C" void kernel_launch(void* const* d_in, const int* in_sizes, int n_in,
                              void* d_out, int out_size, void* d_ws, size_t ws_size,
                              hipStream_t stream) {
    const float* preds = (const float*)d_in[0];
    const float* gts   = (const float*)d_in[1];
    float* out = (float*)d_out;
    unsigned int* wsmin = (unsigned int*)d_ws;   // 512 KB used

    // 0xFF fill = +inf sentinel for uint atomicMin (all finite d bits smaller)
    hipMemsetAsync(wsmin, 0xFF, (size_t)WSMIN_N * sizeof(unsigned int), stream);

    haus_scan_kernel<<<dim3(NHB * SPLIT, NB, 2), dim3(TPB), 0, stream>>>(
        preds, gts, wsmin);

    haus_final_kernel<<<dim3(NB), dim3(TPB), 0, stream>>>(wsmin, out);
}